// Round 5
// baseline (572.468 us; speedup 1.0000x reference)
//
#include <hip/hip_runtime.h>
#include <cstdint>
#include <cstddef>

#define PI_F 3.14159265358979323846f

constexpr int BB = 4, NN = 512, BN = 2048, NBIN = 48;

// ---------------------------------------------------------------- steer (device)
// K2 row ((k*Ipad + i)*2 + v), col o*2+u. Pad rows (i>=I) written as zeros.
__device__ __forceinline__ void steer_one(const float* __restrict__ W, float* __restrict__ K2,
                                          int O, int I, int Ipad, int idx, int total) {
  if (idx >= total) return;
  int i = idx % Ipad;
  int o = (idx / Ipad) % O;
  int k = idx / (Ipad * O);
  int CTc = O * 2;
  size_t r0 = (size_t)((k*Ipad + i)*2 + 0) * CTc + o*2;
  size_t r1 = r0 + CTc;
  if (i >= I) {
    K2[r0] = 0.0f; K2[r0+1] = 0.0f; K2[r1] = 0.0f; K2[r1+1] = 0.0f;
    return;
  }
  int tt = k % 16;
  float ang = (tt + 0.5f) * (2.0f * PI_F / 16.0f) - PI_F;
  float ct = cosf(ang), st = sinf(ang);
  const float* Wp = W + ((size_t)(k*O + o)*I + i) * 4;
  float w00 = Wp[0], w01 = Wp[1], w10 = Wp[2], w11 = Wp[3];
  float rw00 = ct*w00 - st*w10, rw01 = ct*w01 - st*w11;
  float rw10 = st*w00 + ct*w10, rw11 = st*w01 + ct*w11;
  K2[r0 + 0] = rw00*ct - rw01*st;
  K2[r0 + 1] = rw10*ct - rw11*st;
  K2[r1 + 0] = rw00*st + rw01*ct;
  K2[r1 + 1] = rw10*st + rw11*ct;
}

// ---------------------------------------------------------------- setup: prep + all steers
__global__ __launch_bounds__(256) void setup_kernel(
    const float* __restrict__ p0, const float* __restrict__ v0,
    const float* __restrict__ a, const float* __restrict__ other,
    const float* __restrict__ v0enc, float* __restrict__ p1, float* __restrict__ F0,
    const float* Wcf, float* K2CF, const float* Wco, float* K2CO,
    const float* Wc1, float* K2C1, const float* Wc2, float* K2C2,
    const float* Wc3, float* K2C3, const float* Wc4, float* K2C4) {
  int blk = blockIdx.x;
  int t = threadIdx.x;
  if (blk < 8) {
    int n = blk * 256 + t;
    float p0x = p0[n*2], p0y = p0[n*2+1];
    float v0x = v0[n*2], v0y = v0[n*2+1];
    float ax = a[n*2],  ay = a[n*2+1];
    float v1x = v0x + 0.1f*ax, v1y = v0y + 0.1f*ay;
    p1[n*2]   = p0x + 0.1f*(v0x+v1x)*0.5f;
    p1[n*2+1] = p0y + 0.1f*(v0y+v1y)*0.5f;
    float* F = F0 + (size_t)n*48;
    F[0] = v1x; F[1] = v1y;
    for (int c = 0; c < 3; ++c) {
      F[2+c*2]   = other[(n*3+c)*2];
      F[2+c*2+1] = other[(n*3+c)*2+1];
    }
    for (int c = 0; c < 16; ++c) {
      F[8+c*2]   = v0enc[(n*16+c)*2];
      F[8+c*2+1] = v0enc[(n*16+c)*2+1];
    }
    for (int c = 40; c < 48; ++c) F[c] = 0.0f;
  } else if (blk < 80)  steer_one(Wcf, K2CF, 16, 20, 24, (blk-8)*256 + t, 18432);
  else if (blk < 83)  steer_one(Wco, K2CO, 16, 1, 1,   (blk-80)*256 + t, 768);
  else if (blk < 371) steer_one(Wc1, K2C1, 32, 48, 48, (blk-83)*256 + t, 73728);
  else if (blk < 563) steer_one(Wc2, K2C2, 32, 32, 32, (blk-371)*256 + t, 49152);
  else if (blk < 755) steer_one(Wc3, K2C3, 32, 32, 32, (blk-563)*256 + t, 49152);
  else                steer_one(Wc4, K2C4, 1, 32, 32,  (blk-755)*256 + t, 1536);
}

// ---------------------------------------------------------------- pairs + compaction (both tables)
__global__ __launch_bounds__(256) void pairs_all(const float* __restrict__ qry,
                                                 const float* __restrict__ srcF,
                                                 const float* __restrict__ maskF,
                                                 float* __restrict__ wlF, int* __restrict__ plF,
                                                 int* __restrict__ cntF,
                                                 const float* __restrict__ srcO,
                                                 const float* __restrict__ maskO,
                                                 float* __restrict__ wlO, int* __restrict__ plO,
                                                 int* __restrict__ cntO) {
  bool isBox = blockIdx.x >= 512;
  int qblk = isBox ? (blockIdx.x - 512) : blockIdx.x;
  const float* src = isBox ? srcO : srcF;
  const float* mask = isBox ? maskO : maskF;
  float* wlist = isBox ? wlO : wlF;
  int* plist = isBox ? plO : plF;
  int* cnt = isBox ? cntO : cntF;

  int wv = threadIdx.x >> 6;
  int lane = threadIdx.x & 63;
  int q = qblk * 4 + wv;
  int b = q >> 9;
  float qx = qry[q*2], qy = qry[q*2+1];
  const float* sb = src + b*1024;
  const float* mb = mask + (size_t)q*512;
  float* wl = wlist + (size_t)q*512;
  int* pl = plist + (size_t)q*512;
  int base = 0;
  for (int ch = 0; ch < 8; ++ch) {
    int s = ch*64 + lane;
    float sx = sb[s*2], sy = sb[s*2+1];
    float rx = sx - qx, ry = sy - qy;
    float d2 = rx*rx + ry*ry;
    float m = mb[s];
    float wi = fmaxf(1.0f - d2 / 1600.0f, 0.0f);
    float w = wi*wi*wi*m;
    bool pred = w > 0.0f;
    int k = 0;
    if (pred) {
      float dist = sqrtf(d2 + 1e-9f);
      float theta = atan2f(ry, rx);
      int rb = (int)(dist / 40.0f * 3.0f);
      rb = rb > 2 ? 2 : rb;
      float u = (theta + PI_F) / (2.0f * PI_F) * 16.0f;
      int tb = ((int)floorf(u)) & 15;
      k = rb*16 + tb;
    }
    unsigned long long msk = __ballot(pred);
    int before = __popcll(msk & ((1ull<<lane)-1ull));
    if (pred) {
      wl[base + before] = w;
      pl[base + before] = (s<<6) | k;
    }
    base += __popcll(msk);
  }
  if (lane == 0) cnt[q] = base;
}

// ---------------------------------------------------------------- register-bin accumulate
// one wave per (query, channel-slice); k is wave-uniform -> 48-bin accumulator in VGPRs
__device__ __forceinline__ void bin_add(float (&acc)[48], int k, float wf) {
  switch (k) {
#define BCASE(i) case i: acc[i] += wf; break;
    BCASE(0) BCASE(1) BCASE(2) BCASE(3) BCASE(4) BCASE(5) BCASE(6) BCASE(7)
    BCASE(8) BCASE(9) BCASE(10) BCASE(11) BCASE(12) BCASE(13) BCASE(14) BCASE(15)
    BCASE(16) BCASE(17) BCASE(18) BCASE(19) BCASE(20) BCASE(21) BCASE(22) BCASE(23)
    BCASE(24) BCASE(25) BCASE(26) BCASE(27) BCASE(28) BCASE(29) BCASE(30) BCASE(31)
    BCASE(32) BCASE(33) BCASE(34) BCASE(35) BCASE(36) BCASE(37) BCASE(38) BCASE(39)
    BCASE(40) BCASE(41) BCASE(42) BCASE(43) BCASE(44) BCASE(45) BCASE(46) BCASE(47)
#undef BCASE
    default: break;
  }
}

template<int C2, int HALVES>
__global__ __launch_bounds__(256) void accum_reg(const float* __restrict__ wlist,
                                                 const int* __restrict__ plist,
                                                 const int* __restrict__ cnt,
                                                 const float* __restrict__ feats,
                                                 float* __restrict__ Mout) {
  constexpr int CW = C2 / HALVES;   // channels per wave (<= 64)
  constexpr int Kd = NBIN * C2;
  const int lane = threadIdx.x & 63;
  const int wid = blockIdx.x * 4 + (threadIdx.x >> 6);
  const int q = wid / HALVES;
  const int half = wid % HALVES;
  const int c = half * CW + lane;
  const bool act = lane < CW;
  const int nnz = cnt[q];
  const float* __restrict__ wl = wlist + (size_t)q * 512;
  const int* __restrict__ pl = plist + (size_t)q * 512;
  const float* __restrict__ fb = feats + (size_t)(q >> 9) * 512 * C2 + (act ? c : 0);
  float acc[48];
  #pragma unroll
  for (int i = 0; i < 48; ++i) acc[i] = 0.0f;

  float wA[4], fA[4]; int pA[4];
  float wB[4], fB[4]; int pB[4];
  #pragma unroll
  for (int j = 0; j < 4; ++j) {
    bool v = j < nnz;
    wA[j] = v ? wl[j] : 0.0f;
    pA[j] = v ? pl[j] : 0;
    fA[j] = fb[(pA[j] >> 6) * C2];
  }
  for (int base = 0; base < nnz; base += 4) {
    #pragma unroll
    for (int j = 0; j < 4; ++j) {
      int idx = base + 4 + j;
      bool v = idx < nnz;
      wB[j] = v ? wl[idx] : 0.0f;
      pB[j] = v ? pl[idx] : 0;
      fB[j] = fb[(pB[j] >> 6) * C2];
    }
    #pragma unroll
    for (int j = 0; j < 4; ++j) bin_add(acc, pA[j] & 63, wA[j] * fA[j]);
    #pragma unroll
    for (int j = 0; j < 4; ++j) { wA[j]=wB[j]; pA[j]=pB[j]; fA[j]=fB[j]; }
  }
  if (act) {
    float* mo = Mout + (size_t)q * Kd + c;
    #pragma unroll
    for (int k = 0; k < 48; ++k) mo[k * C2] = acc[k];
  }
}

// ---------------------------------------------------------------- LDS accumulate (box conv, C2=2)
template<int C2, int QB, int TPB>
__global__ __launch_bounds__(TPB) void accum_lds(const float* __restrict__ wlist,
                                                 const int* __restrict__ plist,
                                                 const int* __restrict__ cnt,
                                                 const float* __restrict__ feats,
                                                 float* __restrict__ Mout) {
  constexpr int Kd = NBIN * C2;
  static_assert(TPB == QB * C2, "TPB must equal QB*C2");
  __shared__ float Ml[QB * Kd];
  __shared__ int csh[QB];
  const int t = threadIdx.x;
  const int q0 = blockIdx.x * QB;
  for (int i = t; i < QB*Kd; i += TPB) Ml[i] = 0.0f;
  if (t < QB) csh[t] = cnt[q0 + t];
  __syncthreads();
  const int ql = t / C2, c = t % C2;
  const int q = q0 + ql;
  const int nnz = csh[ql];
  float* M = Ml + ql*Kd + c;
  const float* wls = wlist + (size_t)q*512;
  const int* pls = plist + (size_t)q*512;
  const float* fb = feats + (size_t)(q >> 9) * 512 * C2 + c;
  float wA[4], fA[4]; int kA[4];
  float wB[4], fB[4]; int kB[4];
  #pragma unroll
  for (int j = 0; j < 4; ++j) {
    bool v = j < nnz;
    float w = v ? wls[j] : 0.0f;
    int p = v ? pls[j] : 0;
    wA[j] = w; kA[j] = (p & 63) * C2;
    fA[j] = fb[(p >> 6) * C2];
  }
  for (int base = 0; base < nnz; base += 4) {
    if (base + 4 < nnz) {
      #pragma unroll
      for (int j = 0; j < 4; ++j) {
        int idx = base + 4 + j;
        bool v = idx < nnz;
        float w = v ? wls[idx] : 0.0f;
        int p = v ? pls[idx] : 0;
        wB[j] = w; kB[j] = (p & 63) * C2;
        fB[j] = fb[(p >> 6) * C2];
      }
    }
    #pragma unroll
    for (int j = 0; j < 4; ++j) M[kA[j]] += wA[j] * fA[j];
    #pragma unroll
    for (int j = 0; j < 4; ++j) { wA[j] = wB[j]; kA[j] = kB[j]; fA[j] = fB[j]; }
  }
  __syncthreads();
  float4* dst = (float4*)(Mout + (size_t)q0 * Kd);
  const float4* src4 = (const float4*)Ml;
  for (int i = t; i < QB*Kd/4; i += TPB) dst[i] = src4[i];
}

// ---------------------------------------------------------------- tiled fp32 GEMM with k-split
template<int CT>
__global__ __launch_bounds__(256) void gemm_tiled(const float* __restrict__ A,
                                                  const float* __restrict__ B,
                                                  float* __restrict__ G, int Kdim, int kps) {
  __shared__ float At[16][64];
  __shared__ float Bt[16][CT];
  const int t = threadIdx.x;
  const int row0 = blockIdx.x * 64;
  const int kbeg = blockIdx.y * kps;
  constexpr int CQ = CT / 4;
  constexpr int RGN = 256 / CQ;
  constexpr int RPT = 64 / RGN;
  const int cq = t % CQ;
  const int rg = t / CQ;
  float acc[RPT][4];
  #pragma unroll
  for (int r = 0; r < RPT; ++r)
    for (int cc = 0; cc < 4; ++cc) acc[r][cc] = 0.0f;
  const int arow = t >> 2, akq = t & 3;
  for (int kt = 0; kt < kps; kt += 16) {
    const int k0 = kbeg + kt;
    float4 av4 = *(const float4*)(A + (size_t)(row0 + arow) * Kdim + (k0 + akq*4));
    At[akq*4+0][arow] = av4.x;
    At[akq*4+1][arow] = av4.y;
    At[akq*4+2][arow] = av4.z;
    At[akq*4+3][arow] = av4.w;
    if (CT == 64) {
      int kk = t >> 4, col = (t & 15) * 4;
      *(float4*)&Bt[kk][col] = *(const float4*)(B + (size_t)(k0+kk)*CT + col);
    } else if (t < 128) {
      int kk = t >> 3, col = (t & 7) * 4;
      *(float4*)&Bt[kk][col] = *(const float4*)(B + (size_t)(k0+kk)*CT + col);
    }
    __syncthreads();
    #pragma unroll
    for (int kk = 0; kk < 16; ++kk) {
      float4 bv = *(const float4*)&Bt[kk][cq*4];
      if (RPT == 4) {
        float4 a4 = *(const float4*)&At[kk][rg*4];
        acc[0][0] += a4.x*bv.x; acc[0][1] += a4.x*bv.y; acc[0][2] += a4.x*bv.z; acc[0][3] += a4.x*bv.w;
        acc[1][0] += a4.y*bv.x; acc[1][1] += a4.y*bv.y; acc[1][2] += a4.y*bv.z; acc[1][3] += a4.y*bv.w;
        acc[2][0] += a4.z*bv.x; acc[2][1] += a4.z*bv.y; acc[2][2] += a4.z*bv.z; acc[2][3] += a4.z*bv.w;
        acc[3][0] += a4.w*bv.x; acc[3][1] += a4.w*bv.y; acc[3][2] += a4.w*bv.z; acc[3][3] += a4.w*bv.w;
      } else {
        float2 a2 = *(const float2*)&At[kk][rg*2];
        acc[0][0] += a2.x*bv.x; acc[0][1] += a2.x*bv.y; acc[0][2] += a2.x*bv.z; acc[0][3] += a2.x*bv.w;
        acc[1][0] += a2.y*bv.x; acc[1][1] += a2.y*bv.y; acc[1][2] += a2.y*bv.z; acc[1][3] += a2.y*bv.w;
      }
    }
    __syncthreads();
  }
  const size_t zoff = (size_t)blockIdx.y * BN;
  for (int r = 0; r < RPT; ++r) {
    int row = row0 + rg*RPT + r;
    float* gp = G + (zoff + row) * CT + cq*4;
    gp[0] = acc[r][0]; gp[1] = acc[r][1]; gp[2] = acc[r][2]; gp[3] = acc[r][3];
  }
}

// ---------------------------------------------------------------- stage-0 epilogue
__global__ void epilogue0(const float* __restrict__ Gpf, const float* __restrict__ Gpo,
                          const float* __restrict__ F0, const float* __restrict__ Adf,
                          const float* __restrict__ Bdf, float* __restrict__ in1,
                          int SPF, int SPO) {
  int idx = blockIdx.x * blockDim.x + threadIdx.x;  // q*48+ch
  if (idx >= BN*48) return;
  int ch = idx % 48, q = idx / 48;
  float x = 0.0f, y = 0.0f;
  if (ch < 16) {
    for (int sp = 0; sp < SPO; ++sp) {
      size_t base = ((size_t)sp*BN + q)*32 + ch*2;
      x += Gpo[base]; y += Gpo[base+1];
    }
  } else if (ch < 32) {
    int o = ch - 16;
    for (int sp = 0; sp < SPF; ++sp) {
      size_t base = ((size_t)sp*BN + q)*32 + o*2;
      x += Gpf[base]; y += Gpf[base+1];
    }
  } else {
    int o = ch - 32;
    const float* f = F0 + (size_t)q*48;
    for (int i = 0; i < 20; ++i) {
      float fx = f[i*2], fy = f[i*2+1];
      float Av = Adf[o*20+i], Bv = Bdf[o*20+i];
      x += Av*fx - Bv*fy;
      y += Av*fy + Bv*fx;
    }
  }
  float m = x*x + y*y + 1e-6f;
  float sc = fmaxf(m - 0.2f, 0.0f) / m;
  in1[(size_t)idx*2]   = x * sc;
  in1[(size_t)idx*2+1] = y * sc;
}

// ---------------------------------------------------------------- layer epilogue (layers 1-3)
__global__ void epilogueL(const float* __restrict__ Gp, int SPLIT,
                          const float* __restrict__ inPrev, int I,
                          const float* __restrict__ Ad, const float* __restrict__ Bd,
                          const float* __restrict__ prevOut, int doRes,
                          float* __restrict__ outCur, float* __restrict__ inNext) {
  int idx = blockIdx.x * blockDim.x + threadIdx.x;  // q*32+o
  if (idx >= BN*32) return;
  int o = idx % 32, q = idx / 32;
  float x = 0.0f, y = 0.0f;
  for (int sp = 0; sp < SPLIT; ++sp) {
    size_t base = ((size_t)sp*BN + q)*64 + o*2;
    x += Gp[base]; y += Gp[base+1];
  }
  const float* f = inPrev + (size_t)q * I * 2;
  for (int i = 0; i < I; ++i) {
    float fx = f[i*2], fy = f[i*2+1];
    float Av = Ad[o*I+i], Bv = Bd[o*I+i];
    x += Av*fx - Bv*fy;
    y += Av*fy + Bv*fx;
  }
  if (doRes) {
    x += prevOut[(size_t)idx*2];
    y += prevOut[(size_t)idx*2+1];
  }
  outCur[(size_t)idx*2]   = x;
  outCur[(size_t)idx*2+1] = y;
  float m = x*x + y*y + 1e-6f;
  float sc = fmaxf(m - 0.2f, 0.0f) / m;
  inNext[(size_t)idx*2]   = x * sc;
  inNext[(size_t)idx*2+1] = y * sc;
}

// ---------------------------------------------------------------- layer-4 thin GEMM + apply_correction
__global__ __launch_bounds__(256) void gemm4_final(const float* __restrict__ M,
                                                   const float* __restrict__ K2,
                                                   const float* __restrict__ in4,
                                                   const float* __restrict__ Ad4,
                                                   const float* __restrict__ Bd4,
                                                   const float* __restrict__ p1,
                                                   const float* __restrict__ p0,
                                                   float* __restrict__ dout) {
  int lane = threadIdx.x & 63;
  int wv = threadIdx.x >> 6;
  int q = blockIdx.x * 4 + wv;
  const float* Ar = M + (size_t)q * 3072;
  float a0 = 0.0f, a1 = 0.0f;
  for (int k = lane; k < 3072; k += 64) {
    float av = Ar[k];
    a0 += av * K2[k*2];
    a1 += av * K2[k*2+1];
  }
  if (lane < 32) {
    float fx = in4[q*64 + lane*2], fy = in4[q*64 + lane*2 + 1];
    float Av = Ad4[lane], Bv = Bd4[lane];
    a0 += Av*fx - Bv*fy;
    a1 += Av*fy + Bv*fx;
  }
  for (int off = 32; off > 0; off >>= 1) {
    a0 += __shfl_down(a0, off);
    a1 += __shfl_down(a1, off);
  }
  if (lane == 0) {
    float px = p1[q*2]   + a0/128.0f;
    float py = p1[q*2+1] + a1/128.0f;
    dout[q*2] = px; dout[q*2+1] = py;
    dout[4096 + q*2]   = (px - p0[q*2]) / 0.1f;
    dout[4096 + q*2+1] = (py - p0[q*2+1]) / 0.1f;
  }
}

// ---------------------------------------------------------------- launch
extern "C" void kernel_launch(void* const* d_in, const int* in_sizes, int n_in,
                              void* d_out, int out_size, void* d_ws, size_t ws_size,
                              hipStream_t stream) {
  (void)in_sizes; (void)n_in; (void)out_size; (void)ws_size;
  const float* v0_enc = (const float*)d_in[1];
  const float* p0     = (const float*)d_in[2];
  const float* v0     = (const float*)d_in[3];
  const float* a      = (const float*)d_in[4];
  const float* other  = (const float*)d_in[5];
  const float* box    = (const float*)d_in[6];
  const float* boxf   = (const float*)d_in[7];
  const float* fmask  = (const float*)d_in[8];
  const float* bmask  = (const float*)d_in[9];
  const float* Wcf = (const float*)d_in[10];
  const float* Wco = (const float*)d_in[11];
  const float* Adf = (const float*)d_in[12];
  const float* Bdf = (const float*)d_in[13];
  const float* Wc1 = (const float*)d_in[14];
  const float* Ad1 = (const float*)d_in[15];
  const float* Bd1 = (const float*)d_in[16];
  const float* Wc2 = (const float*)d_in[17];
  const float* Ad2 = (const float*)d_in[18];
  const float* Bd2 = (const float*)d_in[19];
  const float* Wc3 = (const float*)d_in[20];
  const float* Ad3 = (const float*)d_in[21];
  const float* Bd3 = (const float*)d_in[22];
  const float* Wc4 = (const float*)d_in[23];
  const float* Ad4 = (const float*)d_in[24];
  const float* Bd4 = (const float*)d_in[25];

  float* ws = (float*)d_ws;
  float* P1    = ws + 0;          // 4096
  float* F0    = ws + 4096;       // 98304  (stride 48, padded)
  float* K2CF  = ws + 102400;     // 73728  (2304 x 32)
  float* K2CO  = ws + 176128;     // 3072   (96 x 32)
  float* K2C1  = ws + 179200;     // 294912 (4608 x 64)
  float* K2C2  = ws + 474112;     // 196608 (3072 x 64)
  float* K2C3  = ws + 670720;     // 196608
  float* K2C4  = ws + 867328;     // 6144   (3072 x 2)
  float* WFl   = ws + 873472;     // 1048576
  int*   PFl   = (int*)(ws + 1922048);   // 1048576
  int*   CNTF  = (int*)(ws + 2970624);   // 2048
  int*   CNTO  = (int*)(ws + 2972672);   // 2048
  float* IN1   = ws + 2974720;    // 196608 (2048 x 96)
  float* IN2   = ws + 3171328;    // 131072
  float* IN3   = ws + 3302400;    // 131072
  float* IN4   = ws + 3433472;    // 131072
  float* OUTA  = ws + 3564544;    // 131072
  float* OUTB  = ws + 3695616;    // 131072
  float* MO    = ws + 3826688;    // 196608 (box M: 2048 x 96)
  float* GPART = ws + 4027392;    // 2097152 (max 16 x 2048 x 64)
  float* GPF   = GPART;           // 12 x 2048 x 32 = 786432 (stage0 only)
  float* GPO   = GPART + 786432;  // 6 x 2048 x 32 = 393216 (stage0 only)
  float* MBUF  = ws + 6124544;    // 9437184 (max 2048 x 4608)
  float* WOl   = ws + 15561728;   // 1048576
  int*   POl   = (int*)(ws + 16610304);  // 1048576  (end ~70.6 MB)

  setup_kernel<<<761, 256, 0, stream>>>(p0, v0, a, other, v0_enc, P1, F0,
                                        Wcf, K2CF, Wco, K2CO, Wc1, K2C1,
                                        Wc2, K2C2, Wc3, K2C3, Wc4, K2C4);
  pairs_all<<<1024, 256, 0, stream>>>(P1, P1, fmask, WFl, PFl, CNTF,
                                      box, bmask, WOl, POl, CNTO);

  // stage 0
  accum_lds<2, 32, 64><<<64, 64, 0, stream>>>(WOl, POl, CNTO, boxf, MO);
  gemm_tiled<32><<<dim3(32, 6), 256, 0, stream>>>(MO, K2CO, GPO, 96, 16);
  accum_reg<48, 1><<<512, 256, 0, stream>>>(WFl, PFl, CNTF, F0, MBUF);
  gemm_tiled<32><<<dim3(32, 12), 256, 0, stream>>>(MBUF, K2CF, GPF, 2304, 192);
  epilogue0<<<384, 256, 0, stream>>>(GPF, GPO, F0, Adf, Bdf, IN1, 12, 6);

  // layer 1: I=48 -> O=32
  accum_reg<96, 2><<<1024, 256, 0, stream>>>(WFl, PFl, CNTF, IN1, MBUF);
  gemm_tiled<64><<<dim3(32, 16), 256, 0, stream>>>(MBUF, K2C1, GPART, 4608, 288);
  epilogueL<<<256, 256, 0, stream>>>(GPART, 16, IN1, 48, Ad1, Bd1, nullptr, 0, OUTA, IN2);

  // layer 2: I=32 -> O=32, residual
  accum_reg<64, 1><<<512, 256, 0, stream>>>(WFl, PFl, CNTF, IN2, MBUF);
  gemm_tiled<64><<<dim3(32, 12), 256, 0, stream>>>(MBUF, K2C2, GPART, 3072, 256);
  epilogueL<<<256, 256, 0, stream>>>(GPART, 12, IN2, 32, Ad2, Bd2, OUTA, 1, OUTB, IN3);

  // layer 3: I=32 -> O=32, residual
  accum_reg<64, 1><<<512, 256, 0, stream>>>(WFl, PFl, CNTF, IN3, MBUF);
  gemm_tiled<64><<<dim3(32, 12), 256, 0, stream>>>(MBUF, K2C3, GPART, 3072, 256);
  epilogueL<<<256, 256, 0, stream>>>(GPART, 12, IN3, 32, Ad3, Bd3, OUTB, 1, OUTA, IN4);

  // layer 4: I=32 -> O=1, fused thin GEMM + apply_correction
  accum_reg<64, 1><<<512, 256, 0, stream>>>(WFl, PFl, CNTF, IN4, MBUF);
  gemm4_final<<<512, 256, 0, stream>>>(MBUF, K2C4, IN4, Ad4, Bd4, P1, p0, (float*)d_out);
}

// Round 6
// 482.335 us; speedup vs baseline: 1.1869x; 1.1869x over previous
//
#include <hip/hip_runtime.h>
#include <cstdint>
#include <cstddef>

#define PI_F 3.14159265358979323846f

constexpr int BB = 4, NN = 512, BN = 2048, NBIN = 48;

// ---------------------------------------------------------------- steer (device)
__device__ __forceinline__ void steer_one(const float* __restrict__ W, float* __restrict__ K2,
                                          int O, int I, int Ipad, int idx, int total) {
  if (idx >= total) return;
  int i = idx % Ipad;
  int o = (idx / Ipad) % O;
  int k = idx / (Ipad * O);
  int CTc = O * 2;
  size_t r0 = (size_t)((k*Ipad + i)*2 + 0) * CTc + o*2;
  size_t r1 = r0 + CTc;
  if (i >= I) {
    K2[r0] = 0.0f; K2[r0+1] = 0.0f; K2[r1] = 0.0f; K2[r1+1] = 0.0f;
    return;
  }
  int tt = k % 16;
  float ang = (tt + 0.5f) * (2.0f * PI_F / 16.0f) - PI_F;
  float ct = cosf(ang), st = sinf(ang);
  const float* Wp = W + ((size_t)(k*O + o)*I + i) * 4;
  float w00 = Wp[0], w01 = Wp[1], w10 = Wp[2], w11 = Wp[3];
  float rw00 = ct*w00 - st*w10, rw01 = ct*w01 - st*w11;
  float rw10 = st*w00 + ct*w10, rw11 = st*w01 + ct*w11;
  K2[r0 + 0] = rw00*ct - rw01*st;
  K2[r0 + 1] = rw10*ct - rw11*st;
  K2[r1 + 0] = rw00*st + rw01*ct;
  K2[r1 + 1] = rw10*st + rw11*ct;
}

// ---------------------------------------------------------------- setup: prep + all steers
__global__ __launch_bounds__(256) void setup_kernel(
    const float* __restrict__ p0, const float* __restrict__ v0,
    const float* __restrict__ a, const float* __restrict__ other,
    const float* __restrict__ v0enc, float* __restrict__ p1, float* __restrict__ F0,
    const float* Wcf, float* K2CF, const float* Wco, float* K2CO,
    const float* Wc1, float* K2C1, const float* Wc2, float* K2C2,
    const float* Wc3, float* K2C3, const float* Wc4, float* K2C4) {
  int blk = blockIdx.x;
  int t = threadIdx.x;
  if (blk < 8) {
    int n = blk * 256 + t;
    float p0x = p0[n*2], p0y = p0[n*2+1];
    float v0x = v0[n*2], v0y = v0[n*2+1];
    float ax = a[n*2],  ay = a[n*2+1];
    float v1x = v0x + 0.1f*ax, v1y = v0y + 0.1f*ay;
    p1[n*2]   = p0x + 0.1f*(v0x+v1x)*0.5f;
    p1[n*2+1] = p0y + 0.1f*(v0y+v1y)*0.5f;
    float* F = F0 + (size_t)n*48;
    F[0] = v1x; F[1] = v1y;
    for (int c = 0; c < 3; ++c) {
      F[2+c*2]   = other[(n*3+c)*2];
      F[2+c*2+1] = other[(n*3+c)*2+1];
    }
    for (int c = 0; c < 16; ++c) {
      F[8+c*2]   = v0enc[(n*16+c)*2];
      F[8+c*2+1] = v0enc[(n*16+c)*2+1];
    }
    for (int c = 40; c < 48; ++c) F[c] = 0.0f;
  } else if (blk < 80)  steer_one(Wcf, K2CF, 16, 20, 24, (blk-8)*256 + t, 18432);
  else if (blk < 83)  steer_one(Wco, K2CO, 16, 1, 1,   (blk-80)*256 + t, 768);
  else if (blk < 371) steer_one(Wc1, K2C1, 32, 48, 48, (blk-83)*256 + t, 73728);
  else if (blk < 563) steer_one(Wc2, K2C2, 32, 32, 32, (blk-371)*256 + t, 49152);
  else if (blk < 755) steer_one(Wc3, K2C3, 32, 32, 32, (blk-563)*256 + t, 49152);
  else                steer_one(Wc4, K2C4, 1, 32, 32,  (blk-755)*256 + t, 1536);
}

// ---------------------------------------------------------------- pairs: geometry + bin-bucket sort
// one wave per query; entries written grouped (sorted) by bin k; payload (s<<6)|k unchanged
__global__ __launch_bounds__(256) void pairs_all(const float* __restrict__ qry,
                                                 const float* __restrict__ srcF,
                                                 const float* __restrict__ maskF,
                                                 float* __restrict__ wlF, int* __restrict__ plF,
                                                 int* __restrict__ cntF,
                                                 const float* __restrict__ srcO,
                                                 const float* __restrict__ maskO,
                                                 float* __restrict__ wlO, int* __restrict__ plO,
                                                 int* __restrict__ cntO) {
  __shared__ int cnts[4][48];
  bool isBox = blockIdx.x >= 512;
  int qblk = isBox ? (blockIdx.x - 512) : blockIdx.x;
  const float* src = isBox ? srcO : srcF;
  const float* mask = isBox ? maskO : maskF;
  float* wlist = isBox ? wlO : wlF;
  int* plist = isBox ? plO : plF;
  int* cnt = isBox ? cntO : cntF;

  int wv = threadIdx.x >> 6;
  int lane = threadIdx.x & 63;
  int q = qblk * 4 + wv;
  int b = q >> 9;
  float qx = qry[q*2], qy = qry[q*2+1];
  const float* sb = src + b*1024;
  const float* mb = mask + (size_t)q*512;
  float* wl = wlist + (size_t)q*512;
  int* pl = plist + (size_t)q*512;

  float wst[8]; int pst[8];
  #pragma unroll
  for (int ch = 0; ch < 8; ++ch) {
    int s = ch*64 + lane;
    float sx = sb[s*2], sy = sb[s*2+1];
    float rx = sx - qx, ry = sy - qy;
    float d2 = rx*rx + ry*ry;
    float m = mb[s];
    float wi = fmaxf(1.0f - d2 / 1600.0f, 0.0f);
    float w = wi*wi*wi*m;
    int k = 0;
    if (w > 0.0f) {
      float dist = sqrtf(d2 + 1e-9f);
      float theta = atan2f(ry, rx);
      int rb = (int)(dist / 40.0f * 3.0f);
      rb = rb > 2 ? 2 : rb;
      float u = (theta + PI_F) / (2.0f * PI_F) * 16.0f;
      int tb = ((int)floorf(u)) & 15;
      k = rb*16 + tb;
    }
    wst[ch] = w;
    pst[ch] = (s<<6) | k;
  }
  // count per bin
  if (lane < 48) cnts[wv][lane] = 0;
  __syncthreads();
  #pragma unroll
  for (int ch = 0; ch < 8; ++ch)
    if (wst[ch] > 0.0f) atomicAdd(&cnts[wv][pst[ch] & 63], 1);
  __syncthreads();
  // exclusive prefix over 48 bins (in-wave scan)
  int v = (lane < 48) ? cnts[wv][lane] : 0;
  int incl = v;
  #pragma unroll
  for (int d = 1; d < 64; d <<= 1) {
    int tvu = __shfl_up(incl, d);
    if (lane >= d) incl += tvu;
  }
  int excl = incl - v;
  int total = __shfl(incl, 47);
  if (lane < 48) cnts[wv][lane] = excl;
  if (lane == 0) cnt[q] = total;
  __syncthreads();
  // scatter into buckets
  #pragma unroll
  for (int ch = 0; ch < 8; ++ch) {
    if (wst[ch] > 0.0f) {
      int pos = atomicAdd(&cnts[wv][pst[ch] & 63], 1);
      wl[pos] = wst[ch];
      pl[pos] = pst[ch];
    }
  }
}

// ---------------------------------------------------------------- sorted accumulate (no LDS, no atomics)
// one wave per (query, channel-slice); entries sorted by bin -> register accumulator,
// store direct-to-global at each (wave-uniform) bin transition; 8-deep load pipeline
template<int C2, int HALVES>
__global__ __launch_bounds__(256) void accum_sorted(const float* __restrict__ wlist,
                                                    const int* __restrict__ plist,
                                                    const int* __restrict__ cnt,
                                                    const float* __restrict__ feats,
                                                    float* __restrict__ Mout) {
  constexpr int CW = C2 / HALVES;
  constexpr int Kd = NBIN * C2;
  const int lane = threadIdx.x & 63;
  const int wid = blockIdx.x * 4 + (threadIdx.x >> 6);
  const int q = wid / HALVES;
  const int half = wid % HALVES;
  const bool act = lane < CW;
  const int c = half * CW + (act ? lane : 0);
  const int nnz = cnt[q];
  const float* __restrict__ wl = wlist + (size_t)q * 512;
  const int* __restrict__ pl = plist + (size_t)q * 512;
  const float* __restrict__ fb = feats + (size_t)(q >> 9) * 512 * C2 + c;
  float* __restrict__ Mq = Mout + (size_t)q * Kd + c;

  float wA[8], fA[8]; int pA[8];
  #pragma unroll
  for (int j = 0; j < 8; ++j) {
    bool v = j < nnz;
    wA[j] = v ? wl[j] : 0.0f;
    pA[j] = v ? pl[j] : 47;           // pad: s=0, k=47
    fA[j] = fb[(pA[j] >> 6) * C2];
  }
  int kcur = 0;
  float acc = 0.0f;
  for (int base = 0; base < nnz; base += 8) {
    float wB[8], fB[8]; int pB[8];
    #pragma unroll
    for (int j = 0; j < 8; ++j) {
      int idx = base + 8 + j;
      bool v = idx < nnz;
      wB[j] = v ? wl[idx] : 0.0f;
      pB[j] = v ? pl[idx] : 47;
      fB[j] = fb[(pB[j] >> 6) * C2];
    }
    #pragma unroll
    for (int j = 0; j < 8; ++j) {
      int k = pA[j] & 63;             // wave-uniform, non-decreasing
      while (kcur < k) {
        if (act) Mq[kcur * C2] = acc;
        acc = 0.0f;
        ++kcur;
      }
      acc = fmaf(wA[j], fA[j], acc);
    }
    #pragma unroll
    for (int j = 0; j < 8; ++j) { wA[j]=wB[j]; pA[j]=pB[j]; fA[j]=fB[j]; }
  }
  while (kcur < 48) {
    if (act) Mq[kcur * C2] = acc;
    acc = 0.0f;
    ++kcur;
  }
}

// ---------------------------------------------------------------- LDS accumulate (box conv, C2=2)
template<int C2, int QB, int TPB>
__global__ __launch_bounds__(TPB) void accum_lds(const float* __restrict__ wlist,
                                                 const int* __restrict__ plist,
                                                 const int* __restrict__ cnt,
                                                 const float* __restrict__ feats,
                                                 float* __restrict__ Mout) {
  constexpr int Kd = NBIN * C2;
  static_assert(TPB == QB * C2, "TPB must equal QB*C2");
  __shared__ float Ml[QB * Kd];
  __shared__ int csh[QB];
  const int t = threadIdx.x;
  const int q0 = blockIdx.x * QB;
  for (int i = t; i < QB*Kd; i += TPB) Ml[i] = 0.0f;
  if (t < QB) csh[t] = cnt[q0 + t];
  __syncthreads();
  const int ql = t / C2, c = t % C2;
  const int q = q0 + ql;
  const int nnz = csh[ql];
  float* M = Ml + ql*Kd + c;
  const float* wls = wlist + (size_t)q*512;
  const int* pls = plist + (size_t)q*512;
  const float* fb = feats + (size_t)(q >> 9) * 512 * C2 + c;
  float wA[4], fA[4]; int kA[4];
  float wB[4], fB[4]; int kB[4];
  #pragma unroll
  for (int j = 0; j < 4; ++j) {
    bool v = j < nnz;
    float w = v ? wls[j] : 0.0f;
    int p = v ? pls[j] : 0;
    wA[j] = w; kA[j] = (p & 63) * C2;
    fA[j] = fb[(p >> 6) * C2];
  }
  for (int base = 0; base < nnz; base += 4) {
    if (base + 4 < nnz) {
      #pragma unroll
      for (int j = 0; j < 4; ++j) {
        int idx = base + 4 + j;
        bool v = idx < nnz;
        float w = v ? wls[idx] : 0.0f;
        int p = v ? pls[idx] : 0;
        wB[j] = w; kB[j] = (p & 63) * C2;
        fB[j] = fb[(p >> 6) * C2];
      }
    }
    #pragma unroll
    for (int j = 0; j < 4; ++j) M[kA[j]] += wA[j] * fA[j];
    #pragma unroll
    for (int j = 0; j < 4; ++j) { wA[j] = wB[j]; kA[j] = kB[j]; fA[j] = fB[j]; }
  }
  __syncthreads();
  float4* dst = (float4*)(Mout + (size_t)q0 * Kd);
  const float4* src4 = (const float4*)Ml;
  for (int i = t; i < QB*Kd/4; i += TPB) dst[i] = src4[i];
}

// ---------------------------------------------------------------- tiled fp32 GEMM with k-split
template<int CT>
__global__ __launch_bounds__(256) void gemm_tiled(const float* __restrict__ A,
                                                  const float* __restrict__ B,
                                                  float* __restrict__ G, int Kdim, int kps) {
  __shared__ float At[16][64];
  __shared__ float Bt[16][CT];
  const int t = threadIdx.x;
  const int row0 = blockIdx.x * 64;
  const int kbeg = blockIdx.y * kps;
  constexpr int CQ = CT / 4;
  constexpr int RGN = 256 / CQ;
  constexpr int RPT = 64 / RGN;
  const int cq = t % CQ;
  const int rg = t / CQ;
  float acc[RPT][4];
  #pragma unroll
  for (int r = 0; r < RPT; ++r)
    for (int cc = 0; cc < 4; ++cc) acc[r][cc] = 0.0f;
  const int arow = t >> 2, akq = t & 3;
  for (int kt = 0; kt < kps; kt += 16) {
    const int k0 = kbeg + kt;
    float4 av4 = *(const float4*)(A + (size_t)(row0 + arow) * Kdim + (k0 + akq*4));
    At[akq*4+0][arow] = av4.x;
    At[akq*4+1][arow] = av4.y;
    At[akq*4+2][arow] = av4.z;
    At[akq*4+3][arow] = av4.w;
    if (CT == 64) {
      int kk = t >> 4, col = (t & 15) * 4;
      *(float4*)&Bt[kk][col] = *(const float4*)(B + (size_t)(k0+kk)*CT + col);
    } else if (t < 128) {
      int kk = t >> 3, col = (t & 7) * 4;
      *(float4*)&Bt[kk][col] = *(const float4*)(B + (size_t)(k0+kk)*CT + col);
    }
    __syncthreads();
    #pragma unroll
    for (int kk = 0; kk < 16; ++kk) {
      float4 bv = *(const float4*)&Bt[kk][cq*4];
      if (RPT == 4) {
        float4 a4 = *(const float4*)&At[kk][rg*4];
        acc[0][0] += a4.x*bv.x; acc[0][1] += a4.x*bv.y; acc[0][2] += a4.x*bv.z; acc[0][3] += a4.x*bv.w;
        acc[1][0] += a4.y*bv.x; acc[1][1] += a4.y*bv.y; acc[1][2] += a4.y*bv.z; acc[1][3] += a4.y*bv.w;
        acc[2][0] += a4.z*bv.x; acc[2][1] += a4.z*bv.y; acc[2][2] += a4.z*bv.z; acc[2][3] += a4.z*bv.w;
        acc[3][0] += a4.w*bv.x; acc[3][1] += a4.w*bv.y; acc[3][2] += a4.w*bv.z; acc[3][3] += a4.w*bv.w;
      } else {
        float2 a2 = *(const float2*)&At[kk][rg*2];
        acc[0][0] += a2.x*bv.x; acc[0][1] += a2.x*bv.y; acc[0][2] += a2.x*bv.z; acc[0][3] += a2.x*bv.w;
        acc[1][0] += a2.y*bv.x; acc[1][1] += a2.y*bv.y; acc[1][2] += a2.y*bv.z; acc[1][3] += a2.y*bv.w;
      }
    }
    __syncthreads();
  }
  const size_t zoff = (size_t)blockIdx.y * BN;
  for (int r = 0; r < RPT; ++r) {
    int row = row0 + rg*RPT + r;
    float* gp = G + (zoff + row) * CT + cq*4;
    gp[0] = acc[r][0]; gp[1] = acc[r][1]; gp[2] = acc[r][2]; gp[3] = acc[r][3];
  }
}

// ---------------------------------------------------------------- stage-0 epilogue
__global__ void epilogue0(const float* __restrict__ Gpf, const float* __restrict__ Gpo,
                          const float* __restrict__ F0, const float* __restrict__ Adf,
                          const float* __restrict__ Bdf, float* __restrict__ in1,
                          int SPF, int SPO) {
  int idx = blockIdx.x * blockDim.x + threadIdx.x;  // q*48+ch
  if (idx >= BN*48) return;
  int ch = idx % 48, q = idx / 48;
  float x = 0.0f, y = 0.0f;
  if (ch < 16) {
    for (int sp = 0; sp < SPO; ++sp) {
      size_t base = ((size_t)sp*BN + q)*32 + ch*2;
      x += Gpo[base]; y += Gpo[base+1];
    }
  } else if (ch < 32) {
    int o = ch - 16;
    for (int sp = 0; sp < SPF; ++sp) {
      size_t base = ((size_t)sp*BN + q)*32 + o*2;
      x += Gpf[base]; y += Gpf[base+1];
    }
  } else {
    int o = ch - 32;
    const float* f = F0 + (size_t)q*48;
    for (int i = 0; i < 20; ++i) {
      float fx = f[i*2], fy = f[i*2+1];
      float Av = Adf[o*20+i], Bv = Bdf[o*20+i];
      x += Av*fx - Bv*fy;
      y += Av*fy + Bv*fx;
    }
  }
  float m = x*x + y*y + 1e-6f;
  float sc = fmaxf(m - 0.2f, 0.0f) / m;
  in1[(size_t)idx*2]   = x * sc;
  in1[(size_t)idx*2+1] = y * sc;
}

// ---------------------------------------------------------------- layer epilogue (layers 1-3)
__global__ void epilogueL(const float* __restrict__ Gp, int SPLIT,
                          const float* __restrict__ inPrev, int I,
                          const float* __restrict__ Ad, const float* __restrict__ Bd,
                          const float* __restrict__ prevOut, int doRes,
                          float* __restrict__ outCur, float* __restrict__ inNext) {
  int idx = blockIdx.x * blockDim.x + threadIdx.x;  // q*32+o
  if (idx >= BN*32) return;
  int o = idx % 32, q = idx / 32;
  float x = 0.0f, y = 0.0f;
  for (int sp = 0; sp < SPLIT; ++sp) {
    size_t base = ((size_t)sp*BN + q)*64 + o*2;
    x += Gp[base]; y += Gp[base+1];
  }
  const float* f = inPrev + (size_t)q * I * 2;
  for (int i = 0; i < I; ++i) {
    float fx = f[i*2], fy = f[i*2+1];
    float Av = Ad[o*I+i], Bv = Bd[o*I+i];
    x += Av*fx - Bv*fy;
    y += Av*fy + Bv*fx;
  }
  if (doRes) {
    x += prevOut[(size_t)idx*2];
    y += prevOut[(size_t)idx*2+1];
  }
  outCur[(size_t)idx*2]   = x;
  outCur[(size_t)idx*2+1] = y;
  float m = x*x + y*y + 1e-6f;
  float sc = fmaxf(m - 0.2f, 0.0f) / m;
  inNext[(size_t)idx*2]   = x * sc;
  inNext[(size_t)idx*2+1] = y * sc;
}

// ---------------------------------------------------------------- layer-4 thin GEMM + apply_correction
__global__ __launch_bounds__(256) void gemm4_final(const float* __restrict__ M,
                                                   const float* __restrict__ K2,
                                                   const float* __restrict__ in4,
                                                   const float* __restrict__ Ad4,
                                                   const float* __restrict__ Bd4,
                                                   const float* __restrict__ p1,
                                                   const float* __restrict__ p0,
                                                   float* __restrict__ dout) {
  int lane = threadIdx.x & 63;
  int wv = threadIdx.x >> 6;
  int q = blockIdx.x * 4 + wv;
  const float* Ar = M + (size_t)q * 3072;
  float a0 = 0.0f, a1 = 0.0f;
  for (int k = lane; k < 3072; k += 64) {
    float av = Ar[k];
    a0 += av * K2[k*2];
    a1 += av * K2[k*2+1];
  }
  if (lane < 32) {
    float fx = in4[q*64 + lane*2], fy = in4[q*64 + lane*2 + 1];
    float Av = Ad4[lane], Bv = Bd4[lane];
    a0 += Av*fx - Bv*fy;
    a1 += Av*fy + Bv*fx;
  }
  for (int off = 32; off > 0; off >>= 1) {
    a0 += __shfl_down(a0, off);
    a1 += __shfl_down(a1, off);
  }
  if (lane == 0) {
    float px = p1[q*2]   + a0/128.0f;
    float py = p1[q*2+1] + a1/128.0f;
    dout[q*2] = px; dout[q*2+1] = py;
    dout[4096 + q*2]   = (px - p0[q*2]) / 0.1f;
    dout[4096 + q*2+1] = (py - p0[q*2+1]) / 0.1f;
  }
}

// ---------------------------------------------------------------- launch
extern "C" void kernel_launch(void* const* d_in, const int* in_sizes, int n_in,
                              void* d_out, int out_size, void* d_ws, size_t ws_size,
                              hipStream_t stream) {
  (void)in_sizes; (void)n_in; (void)out_size; (void)ws_size;
  const float* v0_enc = (const float*)d_in[1];
  const float* p0     = (const float*)d_in[2];
  const float* v0     = (const float*)d_in[3];
  const float* a      = (const float*)d_in[4];
  const float* other  = (const float*)d_in[5];
  const float* box    = (const float*)d_in[6];
  const float* boxf   = (const float*)d_in[7];
  const float* fmask  = (const float*)d_in[8];
  const float* bmask  = (const float*)d_in[9];
  const float* Wcf = (const float*)d_in[10];
  const float* Wco = (const float*)d_in[11];
  const float* Adf = (const float*)d_in[12];
  const float* Bdf = (const float*)d_in[13];
  const float* Wc1 = (const float*)d_in[14];
  const float* Ad1 = (const float*)d_in[15];
  const float* Bd1 = (const float*)d_in[16];
  const float* Wc2 = (const float*)d_in[17];
  const float* Ad2 = (const float*)d_in[18];
  const float* Bd2 = (const float*)d_in[19];
  const float* Wc3 = (const float*)d_in[20];
  const float* Ad3 = (const float*)d_in[21];
  const float* Bd3 = (const float*)d_in[22];
  const float* Wc4 = (const float*)d_in[23];
  const float* Ad4 = (const float*)d_in[24];
  const float* Bd4 = (const float*)d_in[25];

  float* ws = (float*)d_ws;
  float* P1    = ws + 0;          // 4096
  float* F0    = ws + 4096;       // 98304  (stride 48, padded)
  float* K2CF  = ws + 102400;     // 73728  (2304 x 32)
  float* K2CO  = ws + 176128;     // 3072   (96 x 32)
  float* K2C1  = ws + 179200;     // 294912 (4608 x 64)
  float* K2C2  = ws + 474112;     // 196608 (3072 x 64)
  float* K2C3  = ws + 670720;     // 196608
  float* K2C4  = ws + 867328;     // 6144   (3072 x 2)
  float* WFl   = ws + 873472;     // 1048576
  int*   PFl   = (int*)(ws + 1922048);   // 1048576
  int*   CNTF  = (int*)(ws + 2970624);   // 2048
  int*   CNTO  = (int*)(ws + 2972672);   // 2048
  float* IN1   = ws + 2974720;    // 196608 (2048 x 96)
  float* IN2   = ws + 3171328;    // 131072
  float* IN3   = ws + 3302400;    // 131072
  float* IN4   = ws + 3433472;    // 131072
  float* OUTA  = ws + 3564544;    // 131072
  float* OUTB  = ws + 3695616;    // 131072
  float* MO    = ws + 3826688;    // 196608 (box M: 2048 x 96)
  float* GPART = ws + 4027392;    // 2097152 (max 16 x 2048 x 64)
  float* GPF   = GPART;           // 12 x 2048 x 32 (stage0 only)
  float* GPO   = GPART + 786432;  // 6 x 2048 x 32 (stage0 only)
  float* MBUF  = ws + 6124544;    // 9437184 (max 2048 x 4608)
  float* WOl   = ws + 15561728;   // 1048576
  int*   POl   = (int*)(ws + 16610304);  // 1048576

  setup_kernel<<<761, 256, 0, stream>>>(p0, v0, a, other, v0_enc, P1, F0,
                                        Wcf, K2CF, Wco, K2CO, Wc1, K2C1,
                                        Wc2, K2C2, Wc3, K2C3, Wc4, K2C4);
  pairs_all<<<1024, 256, 0, stream>>>(P1, P1, fmask, WFl, PFl, CNTF,
                                      box, bmask, WOl, POl, CNTO);

  // stage 0
  accum_lds<2, 32, 64><<<64, 64, 0, stream>>>(WOl, POl, CNTO, boxf, MO);
  gemm_tiled<32><<<dim3(32, 6), 256, 0, stream>>>(MO, K2CO, GPO, 96, 16);
  accum_sorted<48, 1><<<512, 256, 0, stream>>>(WFl, PFl, CNTF, F0, MBUF);
  gemm_tiled<32><<<dim3(32, 12), 256, 0, stream>>>(MBUF, K2CF, GPF, 2304, 192);
  epilogue0<<<384, 256, 0, stream>>>(GPF, GPO, F0, Adf, Bdf, IN1, 12, 6);

  // layer 1: I=48 -> O=32
  accum_sorted<96, 2><<<1024, 256, 0, stream>>>(WFl, PFl, CNTF, IN1, MBUF);
  gemm_tiled<64><<<dim3(32, 16), 256, 0, stream>>>(MBUF, K2C1, GPART, 4608, 288);
  epilogueL<<<256, 256, 0, stream>>>(GPART, 16, IN1, 48, Ad1, Bd1, nullptr, 0, OUTA, IN2);

  // layer 2: I=32 -> O=32, residual
  accum_sorted<64, 1><<<512, 256, 0, stream>>>(WFl, PFl, CNTF, IN2, MBUF);
  gemm_tiled<64><<<dim3(32, 12), 256, 0, stream>>>(MBUF, K2C2, GPART, 3072, 256);
  epilogueL<<<256, 256, 0, stream>>>(GPART, 12, IN2, 32, Ad2, Bd2, OUTA, 1, OUTB, IN3);

  // layer 3: I=32 -> O=32, residual
  accum_sorted<64, 1><<<512, 256, 0, stream>>>(WFl, PFl, CNTF, IN3, MBUF);
  gemm_tiled<64><<<dim3(32, 12), 256, 0, stream>>>(MBUF, K2C3, GPART, 3072, 256);
  epilogueL<<<256, 256, 0, stream>>>(GPART, 12, IN3, 32, Ad3, Bd3, OUTB, 1, OUTA, IN4);

  // layer 4: I=32 -> O=1, fused thin GEMM + apply_correction
  accum_sorted<64, 1><<<512, 256, 0, stream>>>(WFl, PFl, CNTF, IN4, MBUF);
  gemm4_final<<<512, 256, 0, stream>>>(MBUF, K2C4, IN4, Ad4, Bd4, P1, p0, (float*)d_out);
}

// Round 7
// 380.632 us; speedup vs baseline: 1.5040x; 1.2672x over previous
//
#include <hip/hip_runtime.h>
#include <cstdint>
#include <cstddef>

#define PI_F 3.14159265358979323846f

constexpr int BB = 4, NN = 512, BN = 2048, NBIN = 48;

typedef __attribute__((ext_vector_type(8))) short v8s;   // 8 bf16 (4 VGPRs)
typedef __attribute__((ext_vector_type(4))) float v4f;   // MFMA acc

__device__ __forceinline__ unsigned short f2bf(float f) {
  unsigned u = __float_as_uint(f);
  unsigned r = (u + 0x7FFFu + ((u >> 16) & 1u)) >> 16;   // RNE
  return (unsigned short)r;
}
__device__ __forceinline__ float bf2f(unsigned short s) {
  return __uint_as_float(((unsigned)s) << 16);
}

// ---------------------------------------------------------------- steer variants
// fp32, row-major rows=(k*Ipad+i)*2+v, cols=o*2+u (for box conv + layer4 thin)
__device__ __forceinline__ void steer_f32(const float* __restrict__ W, float* __restrict__ K2,
                                          int O, int I, int Ipad, int idx, int total) {
  if (idx >= total) return;
  int i = idx % Ipad;
  int o = (idx / Ipad) % O;
  int k = idx / (Ipad * O);
  int CTc = O * 2;
  size_t r0 = (size_t)((k*Ipad + i)*2 + 0) * CTc + o*2;
  size_t r1 = r0 + CTc;
  if (i >= I) { K2[r0]=0.f; K2[r0+1]=0.f; K2[r1]=0.f; K2[r1+1]=0.f; return; }
  int tt = k % 16;
  float ang = (tt + 0.5f) * (2.0f * PI_F / 16.0f) - PI_F;
  float ct = cosf(ang), st = sinf(ang);
  const float* Wp = W + ((size_t)(k*O + o)*I + i) * 4;
  float w00 = Wp[0], w01 = Wp[1], w10 = Wp[2], w11 = Wp[3];
  float rw00 = ct*w00 - st*w10, rw01 = ct*w01 - st*w11;
  float rw10 = st*w00 + ct*w10, rw11 = st*w01 + ct*w11;
  K2[r0 + 0] = rw00*ct - rw01*st;
  K2[r0 + 1] = rw10*ct - rw11*st;
  K2[r1 + 0] = rw00*st + rw01*ct;
  K2[r1 + 1] = rw10*st + rw11*ct;
}

// bf16 transposed: K2T[(o*2+u)*Kd + (k*Ipad+i)*2+v]  (Kd = NBIN*Ipad*2)
__device__ __forceinline__ void steer_bf16T(const float* __restrict__ W,
                                            unsigned short* __restrict__ K2T,
                                            int O, int I, int Ipad, int Kd,
                                            int idx, int total) {
  if (idx >= total) return;
  int i = idx % Ipad;
  int o = (idx / Ipad) % O;
  int k = idx / (Ipad * O);
  size_t c0 = (size_t)(o*2 + 0) * Kd + (k*Ipad + i)*2;
  size_t c1 = (size_t)(o*2 + 1) * Kd + (k*Ipad + i)*2;
  if (i >= I) { K2T[c0]=0; K2T[c0+1]=0; K2T[c1]=0; K2T[c1+1]=0; return; }
  int tt = k % 16;
  float ang = (tt + 0.5f) * (2.0f * PI_F / 16.0f) - PI_F;
  float ct = cosf(ang), st = sinf(ang);
  const float* Wp = W + ((size_t)(k*O + o)*I + i) * 4;
  float w00 = Wp[0], w01 = Wp[1], w10 = Wp[2], w11 = Wp[3];
  float rw00 = ct*w00 - st*w10, rw01 = ct*w01 - st*w11;
  float rw10 = st*w00 + ct*w10, rw11 = st*w01 + ct*w11;
  // u=0: (k00, k01) over v ; u=1: (k10, k11)
  K2T[c0 + 0] = f2bf(rw00*ct - rw01*st);
  K2T[c0 + 1] = f2bf(rw00*st + rw01*ct);
  K2T[c1 + 0] = f2bf(rw10*ct - rw11*st);
  K2T[c1 + 1] = f2bf(rw10*st + rw11*ct);
}

// ---------------------------------------------------------------- setup: prep + all steers
__global__ __launch_bounds__(256) void setup_kernel(
    const float* __restrict__ p0, const float* __restrict__ v0,
    const float* __restrict__ a, const float* __restrict__ other,
    const float* __restrict__ v0enc, float* __restrict__ p1, float* __restrict__ F0,
    const float* Wcf, unsigned short* K2CF, const float* Wco, float* K2CO,
    const float* Wc1, unsigned short* K2C1, const float* Wc2, unsigned short* K2C2,
    const float* Wc3, unsigned short* K2C3, const float* Wc4, float* K2C4) {
  int blk = blockIdx.x;
  int t = threadIdx.x;
  if (blk < 8) {
    int n = blk * 256 + t;
    float p0x = p0[n*2], p0y = p0[n*2+1];
    float v0x = v0[n*2], v0y = v0[n*2+1];
    float ax = a[n*2],  ay = a[n*2+1];
    float v1x = v0x + 0.1f*ax, v1y = v0y + 0.1f*ay;
    p1[n*2]   = p0x + 0.1f*(v0x+v1x)*0.5f;
    p1[n*2+1] = p0y + 0.1f*(v0y+v1y)*0.5f;
    float* F = F0 + (size_t)n*48;
    F[0] = v1x; F[1] = v1y;
    for (int c = 0; c < 3; ++c) {
      F[2+c*2]   = other[(n*3+c)*2];
      F[2+c*2+1] = other[(n*3+c)*2+1];
    }
    for (int c = 0; c < 16; ++c) {
      F[8+c*2]   = v0enc[(n*16+c)*2];
      F[8+c*2+1] = v0enc[(n*16+c)*2+1];
    }
    for (int c = 40; c < 48; ++c) F[c] = 0.0f;
  } else if (blk < 80)  steer_bf16T(Wcf, K2CF, 16, 20, 24, 2304, (blk-8)*256 + t, 18432);
  else if (blk < 83)  steer_f32(Wco, K2CO, 16, 1, 1,   (blk-80)*256 + t, 768);
  else if (blk < 371) steer_bf16T(Wc1, K2C1, 32, 48, 48, 4608, (blk-83)*256 + t, 73728);
  else if (blk < 563) steer_bf16T(Wc2, K2C2, 32, 32, 32, 3072, (blk-371)*256 + t, 49152);
  else if (blk < 755) steer_bf16T(Wc3, K2C3, 32, 32, 32, 3072, (blk-563)*256 + t, 49152);
  else                steer_f32(Wc4, K2C4, 1, 32, 32,  (blk-755)*256 + t, 1536);
}

// ---------------------------------------------------------------- pairs + compaction (R4 version)
__global__ __launch_bounds__(256) void pairs_all(const float* __restrict__ qry,
                                                 const float* __restrict__ srcF,
                                                 const float* __restrict__ maskF,
                                                 float* __restrict__ wlF, int* __restrict__ plF,
                                                 int* __restrict__ cntF,
                                                 const float* __restrict__ srcO,
                                                 const float* __restrict__ maskO,
                                                 float* __restrict__ wlO, int* __restrict__ plO,
                                                 int* __restrict__ cntO) {
  bool isBox = blockIdx.x >= 512;
  int qblk = isBox ? (blockIdx.x - 512) : blockIdx.x;
  const float* src = isBox ? srcO : srcF;
  const float* mask = isBox ? maskO : maskF;
  float* wlist = isBox ? wlO : wlF;
  int* plist = isBox ? plO : plF;
  int* cnt = isBox ? cntO : cntF;

  int wv = threadIdx.x >> 6;
  int lane = threadIdx.x & 63;
  int q = qblk * 4 + wv;
  int b = q >> 9;
  float qx = qry[q*2], qy = qry[q*2+1];
  const float* sb = src + b*1024;
  const float* mb = mask + (size_t)q*512;
  float* wl = wlist + (size_t)q*512;
  int* pl = plist + (size_t)q*512;
  int base = 0;
  for (int ch = 0; ch < 8; ++ch) {
    int s = ch*64 + lane;
    float sx = sb[s*2], sy = sb[s*2+1];
    float rx = sx - qx, ry = sy - qy;
    float d2 = rx*rx + ry*ry;
    float m = mb[s];
    float wi = fmaxf(1.0f - d2 / 1600.0f, 0.0f);
    float w = wi*wi*wi*m;
    bool pred = w > 0.0f;
    int k = 0;
    if (pred) {
      float dist = sqrtf(d2 + 1e-9f);
      float theta = atan2f(ry, rx);
      int rb = (int)(dist / 40.0f * 3.0f);
      rb = rb > 2 ? 2 : rb;
      float u = (theta + PI_F) / (2.0f * PI_F) * 16.0f;
      int tb = ((int)floorf(u)) & 15;
      k = rb*16 + tb;
    }
    unsigned long long msk = __ballot(pred);
    int before = __popcll(msk & ((1ull<<lane)-1ull));
    if (pred) {
      wl[base + before] = w;
      pl[base + before] = (s<<6) | k;
    }
    base += __popcll(msk);
  }
  if (lane == 0) cnt[q] = base;
}

// ---------------------------------------------------------------- accumulate M -> bf16 (R4 structure)
template<int C2, int QB, int TPB, bool STAGE_LISTS>
__global__ __launch_bounds__(TPB) void accum4(const float* __restrict__ wlist,
                                              const int* __restrict__ plist,
                                              const int* __restrict__ cnt,
                                              const float* __restrict__ feats,
                                              unsigned short* __restrict__ Mout) {
  constexpr int Kd = NBIN * C2;
  static_assert(TPB == QB * C2, "TPB must equal QB*C2");
  __shared__ float Ml[QB * Kd];
  __shared__ float wsh[STAGE_LISTS ? QB*512 : 4];
  __shared__ int   psh[STAGE_LISTS ? QB*512 : 4];
  __shared__ int   csh[QB];
  const int t = threadIdx.x;
  const int q0 = blockIdx.x * QB;
  for (int i = t; i < QB*Kd; i += TPB) Ml[i] = 0.0f;
  if (t < QB) csh[t] = (q0 + t < BN) ? cnt[q0 + t] : 0;
  __syncthreads();
  if (STAGE_LISTS) {
    for (int i = t; i < QB*128; i += TPB) {
      int qs = i >> 7, j = i & 127;
      if (j*4 < csh[qs]) {
        ((float4*)(wsh + qs*512))[j] = ((const float4*)(wlist + (size_t)(q0+qs)*512))[j];
        ((int4*)(psh + qs*512))[j]   = ((const int4*)(plist + (size_t)(q0+qs)*512))[j];
      }
    }
    __syncthreads();
  }
  const int ql = t / C2, c = t % C2;
  const int q = q0 + ql;
  const int nnz = csh[ql];
  float* M = Ml + ql*Kd + c;
  const float* wls; const int* pls;
  if (STAGE_LISTS) { wls = wsh + ql*512; pls = psh + ql*512; }
  else { wls = wlist + (size_t)q*512; pls = plist + (size_t)q*512; }
  const float* fb = feats + (size_t)(q >> 9) * 512 * C2 + c;

  if (nnz > 0) {
    float wA[4], fA[4]; int kA[4];
    float wB[4], fB[4]; int kB[4];
    #pragma unroll
    for (int j = 0; j < 4; ++j) {
      bool v = j < nnz;
      float w = v ? wls[j] : 0.0f;
      int p = v ? pls[j] : 0;
      wA[j] = w; kA[j] = (p & 63) * C2;
      fA[j] = fb[(p >> 6) * C2];
    }
    for (int base = 0; base < nnz; base += 4) {
      if (base + 4 < nnz) {
        #pragma unroll
        for (int j = 0; j < 4; ++j) {
          int idx = base + 4 + j;
          bool v = idx < nnz;
          float w = v ? wls[idx] : 0.0f;
          int p = v ? pls[idx] : 0;
          wB[j] = w; kB[j] = (p & 63) * C2;
          fB[j] = fb[(p >> 6) * C2];
        }
      }
      #pragma unroll
      for (int j = 0; j < 4; ++j) M[kA[j]] += wA[j] * fA[j];
      #pragma unroll
      for (int j = 0; j < 4; ++j) { wA[j] = wB[j]; kA[j] = kB[j]; fA[j] = fB[j]; }
    }
  }
  __syncthreads();
  // write-out as packed bf16
  unsigned* dst = (unsigned*)(Mout + (size_t)q0 * Kd);
  const float2* s2 = (const float2*)Ml;
  const int rows = (q0 + QB <= BN) ? QB : (BN - q0);
  const int lim = rows * (Kd/2);
  for (int i = t; i < lim; i += TPB) {
    float2 v = s2[i];
    dst[i] = (unsigned)f2bf(v.x) | ((unsigned)f2bf(v.y) << 16);
  }
}

// ---------------------------------------------------------------- LDS accumulate (box conv, fp32 out)
template<int C2, int QB, int TPB>
__global__ __launch_bounds__(TPB) void accum_lds(const float* __restrict__ wlist,
                                                 const int* __restrict__ plist,
                                                 const int* __restrict__ cnt,
                                                 const float* __restrict__ feats,
                                                 float* __restrict__ Mout) {
  constexpr int Kd = NBIN * C2;
  static_assert(TPB == QB * C2, "TPB must equal QB*C2");
  __shared__ float Ml[QB * Kd];
  __shared__ int csh[QB];
  const int t = threadIdx.x;
  const int q0 = blockIdx.x * QB;
  for (int i = t; i < QB*Kd; i += TPB) Ml[i] = 0.0f;
  if (t < QB) csh[t] = cnt[q0 + t];
  __syncthreads();
  const int ql = t / C2, c = t % C2;
  const int q = q0 + ql;
  const int nnz = csh[ql];
  float* M = Ml + ql*Kd + c;
  const float* wls = wlist + (size_t)q*512;
  const int* pls = plist + (size_t)q*512;
  const float* fb = feats + (size_t)(q >> 9) * 512 * C2 + c;
  if (nnz > 0) {
    float wA[4], fA[4]; int kA[4];
    float wB[4], fB[4]; int kB[4];
    #pragma unroll
    for (int j = 0; j < 4; ++j) {
      bool v = j < nnz;
      float w = v ? wls[j] : 0.0f;
      int p = v ? pls[j] : 0;
      wA[j] = w; kA[j] = (p & 63) * C2;
      fA[j] = fb[(p >> 6) * C2];
    }
    for (int base = 0; base < nnz; base += 4) {
      if (base + 4 < nnz) {
        #pragma unroll
        for (int j = 0; j < 4; ++j) {
          int idx = base + 4 + j;
          bool v = idx < nnz;
          float w = v ? wls[idx] : 0.0f;
          int p = v ? pls[idx] : 0;
          wB[j] = w; kB[j] = (p & 63) * C2;
          fB[j] = fb[(p >> 6) * C2];
        }
      }
      #pragma unroll
      for (int j = 0; j < 4; ++j) M[kA[j]] += wA[j] * fA[j];
      #pragma unroll
      for (int j = 0; j < 4; ++j) { wA[j] = wB[j]; kA[j] = kB[j]; fA[j] = fB[j]; }
    }
  }
  __syncthreads();
  float4* dst = (float4*)(Mout + (size_t)q0 * Kd);
  const float4* src4 = (const float4*)Ml;
  for (int i = t; i < QB*Kd/4; i += TPB) dst[i] = src4[i];
}

// ---------------------------------------------------------------- bf16 MFMA GEMM with k-split
// A: Mbf [2048][Kd] bf16; B: K2T [CT][Kd] bf16 (col-major view); G: fp32 [SPLIT][2048][CT]
// wave = 32 rows (2 m-tiles) x CT cols over its k-slice; block = 4 waves = 4 k-splits
template<int CT>
__global__ __launch_bounds__(256) void gemm_mfma(const unsigned short* __restrict__ A,
                                                 const unsigned short* __restrict__ B,
                                                 float* __restrict__ G, int Kd, int kn) {
  const int lane = threadIdx.x & 63;
  const int w = threadIdx.x >> 6;
  const int mblk = blockIdx.x;                 // 32 rows each (2048/32 = 64)
  const int ks = blockIdx.y * 4 + w;           // k-split id
  const int k0 = ks * kn;
  const int m = lane & 15, quad = lane >> 4;
  constexpr int NT = CT / 16;
  const unsigned short* Ar0 = A + (size_t)(mblk*32 + m) * Kd + k0 + quad*8;
  const unsigned short* Ar1 = Ar0 + (size_t)16 * Kd;
  const unsigned short* Bp[NT];
  #pragma unroll
  for (int nt = 0; nt < NT; ++nt)
    Bp[nt] = B + (size_t)(nt*16 + m) * Kd + k0 + quad*8;
  v4f acc[2][NT];
  #pragma unroll
  for (int mt = 0; mt < 2; ++mt)
    for (int nt = 0; nt < NT; ++nt)
      acc[mt][nt] = (v4f){0.0f, 0.0f, 0.0f, 0.0f};
  for (int kt = 0; kt < kn; kt += 32) {
    v8s a0 = *(const v8s*)(Ar0 + kt);
    v8s a1 = *(const v8s*)(Ar1 + kt);
    #pragma unroll
    for (int nt = 0; nt < NT; ++nt) {
      v8s bv = *(const v8s*)(Bp[nt] + kt);
      acc[0][nt] = __builtin_amdgcn_mfma_f32_16x16x32_bf16(a0, bv, acc[0][nt], 0, 0, 0);
      acc[1][nt] = __builtin_amdgcn_mfma_f32_16x16x32_bf16(a1, bv, acc[1][nt], 0, 0, 0);
    }
  }
  // D layout: col = lane&15, row = quad*4 + reg
  float* Gb = G + ((size_t)ks * BN + mblk*32) * CT;
  #pragma unroll
  for (int mt = 0; mt < 2; ++mt)
    for (int nt = 0; nt < NT; ++nt)
      for (int r = 0; r < 4; ++r)
        Gb[(mt*16 + quad*4 + r) * CT + nt*16 + m] = acc[mt][nt][r];
}

// ---------------------------------------------------------------- fp32 tiled GEMM (box conv only)
template<int CT>
__global__ __launch_bounds__(256) void gemm_tiled(const float* __restrict__ A,
                                                  const float* __restrict__ B,
                                                  float* __restrict__ G, int Kdim, int kps) {
  __shared__ float At[16][64];
  __shared__ float Bt[16][CT];
  const int t = threadIdx.x;
  const int row0 = blockIdx.x * 64;
  const int kbeg = blockIdx.y * kps;
  constexpr int CQ = CT / 4;
  constexpr int RGN = 256 / CQ;
  constexpr int RPT = 64 / RGN;
  const int cq = t % CQ;
  const int rg = t / CQ;
  float acc[RPT][4];
  #pragma unroll
  for (int r = 0; r < RPT; ++r)
    for (int cc = 0; cc < 4; ++cc) acc[r][cc] = 0.0f;
  const int arow = t >> 2, akq = t & 3;
  for (int kt = 0; kt < kps; kt += 16) {
    const int k0 = kbeg + kt;
    float4 av4 = *(const float4*)(A + (size_t)(row0 + arow) * Kdim + (k0 + akq*4));
    At[akq*4+0][arow] = av4.x;
    At[akq*4+1][arow] = av4.y;
    At[akq*4+2][arow] = av4.z;
    At[akq*4+3][arow] = av4.w;
    if (t < 128) {
      int kk = t >> 3, col = (t & 7) * 4;
      *(float4*)&Bt[kk][col] = *(const float4*)(B + (size_t)(k0+kk)*CT + col);
    }
    __syncthreads();
    #pragma unroll
    for (int kk = 0; kk < 16; ++kk) {
      float4 bv = *(const float4*)&Bt[kk][cq*4];
      float2 a2 = *(const float2*)&At[kk][rg*2];
      acc[0][0] += a2.x*bv.x; acc[0][1] += a2.x*bv.y; acc[0][2] += a2.x*bv.z; acc[0][3] += a2.x*bv.w;
      acc[1][0] += a2.y*bv.x; acc[1][1] += a2.y*bv.y; acc[1][2] += a2.y*bv.z; acc[1][3] += a2.y*bv.w;
    }
    __syncthreads();
  }
  const size_t zoff = (size_t)blockIdx.y * BN;
  for (int r = 0; r < RPT; ++r) {
    int row = row0 + rg*RPT + r;
    float* gp = G + (zoff + row) * CT + cq*4;
    gp[0] = acc[r][0]; gp[1] = acc[r][1]; gp[2] = acc[r][2]; gp[3] = acc[r][3];
  }
}

// ---------------------------------------------------------------- stage-0 epilogue
__global__ void epilogue0(const float* __restrict__ Gpf, const float* __restrict__ Gpo,
                          const float* __restrict__ F0, const float* __restrict__ Adf,
                          const float* __restrict__ Bdf, float* __restrict__ in1,
                          int SPF, int SPO) {
  int idx = blockIdx.x * blockDim.x + threadIdx.x;  // q*48+ch
  if (idx >= BN*48) return;
  int ch = idx % 48, q = idx / 48;
  float x = 0.0f, y = 0.0f;
  if (ch < 16) {
    for (int sp = 0; sp < SPO; ++sp) {
      size_t base = ((size_t)sp*BN + q)*32 + ch*2;
      x += Gpo[base]; y += Gpo[base+1];
    }
  } else if (ch < 32) {
    int o = ch - 16;
    for (int sp = 0; sp < SPF; ++sp) {
      size_t base = ((size_t)sp*BN + q)*32 + o*2;
      x += Gpf[base]; y += Gpf[base+1];
    }
  } else {
    int o = ch - 32;
    const float* f = F0 + (size_t)q*48;
    for (int i = 0; i < 20; ++i) {
      float fx = f[i*2], fy = f[i*2+1];
      float Av = Adf[o*20+i], Bv = Bdf[o*20+i];
      x += Av*fx - Bv*fy;
      y += Av*fy + Bv*fx;
    }
  }
  float m = x*x + y*y + 1e-6f;
  float sc = fmaxf(m - 0.2f, 0.0f) / m;
  in1[(size_t)idx*2]   = x * sc;
  in1[(size_t)idx*2+1] = y * sc;
}

// ---------------------------------------------------------------- layer epilogue (layers 1-3)
__global__ void epilogueL(const float* __restrict__ Gp, int SPLIT,
                          const float* __restrict__ inPrev, int I,
                          const float* __restrict__ Ad, const float* __restrict__ Bd,
                          const float* __restrict__ prevOut, int doRes,
                          float* __restrict__ outCur, float* __restrict__ inNext) {
  int idx = blockIdx.x * blockDim.x + threadIdx.x;  // q*32+o
  if (idx >= BN*32) return;
  int o = idx % 32, q = idx / 32;
  float x = 0.0f, y = 0.0f;
  for (int sp = 0; sp < SPLIT; ++sp) {
    size_t base = ((size_t)sp*BN + q)*64 + o*2;
    x += Gp[base]; y += Gp[base+1];
  }
  const float* f = inPrev + (size_t)q * I * 2;
  for (int i = 0; i < I; ++i) {
    float fx = f[i*2], fy = f[i*2+1];
    float Av = Ad[o*I+i], Bv = Bd[o*I+i];
    x += Av*fx - Bv*fy;
    y += Av*fy + Bv*fx;
  }
  if (doRes) {
    x += prevOut[(size_t)idx*2];
    y += prevOut[(size_t)idx*2+1];
  }
  outCur[(size_t)idx*2]   = x;
  outCur[(size_t)idx*2+1] = y;
  float m = x*x + y*y + 1e-6f;
  float sc = fmaxf(m - 0.2f, 0.0f) / m;
  inNext[(size_t)idx*2]   = x * sc;
  inNext[(size_t)idx*2+1] = y * sc;
}

// ---------------------------------------------------------------- layer-4 thin GEMM + apply_correction
__global__ __launch_bounds__(256) void gemm4_final(const unsigned short* __restrict__ M,
                                                   const float* __restrict__ K2,
                                                   const float* __restrict__ in4,
                                                   const float* __restrict__ Ad4,
                                                   const float* __restrict__ Bd4,
                                                   const float* __restrict__ p1,
                                                   const float* __restrict__ p0,
                                                   float* __restrict__ dout) {
  int lane = threadIdx.x & 63;
  int wv = threadIdx.x >> 6;
  int q = blockIdx.x * 4 + wv;
  const unsigned short* Ar = M + (size_t)q * 3072;
  float a0 = 0.0f, a1 = 0.0f;
  for (int k = lane; k < 3072; k += 64) {
    float av = bf2f(Ar[k]);
    a0 += av * K2[k*2];
    a1 += av * K2[k*2+1];
  }
  if (lane < 32) {
    float fx = in4[q*64 + lane*2], fy = in4[q*64 + lane*2 + 1];
    float Av = Ad4[lane], Bv = Bd4[lane];
    a0 += Av*fx - Bv*fy;
    a1 += Av*fy + Bv*fx;
  }
  for (int off = 32; off > 0; off >>= 1) {
    a0 += __shfl_down(a0, off);
    a1 += __shfl_down(a1, off);
  }
  if (lane == 0) {
    float px = p1[q*2]   + a0/128.0f;
    float py = p1[q*2+1] + a1/128.0f;
    dout[q*2] = px; dout[q*2+1] = py;
    dout[4096 + q*2]   = (px - p0[q*2]) / 0.1f;
    dout[4096 + q*2+1] = (py - p0[q*2+1]) / 0.1f;
  }
}

// ---------------------------------------------------------------- launch
extern "C" void kernel_launch(void* const* d_in, const int* in_sizes, int n_in,
                              void* d_out, int out_size, void* d_ws, size_t ws_size,
                              hipStream_t stream) {
  (void)in_sizes; (void)n_in; (void)out_size; (void)ws_size;
  const float* v0_enc = (const float*)d_in[1];
  const float* p0     = (const float*)d_in[2];
  const float* v0     = (const float*)d_in[3];
  const float* a      = (const float*)d_in[4];
  const float* other  = (const float*)d_in[5];
  const float* box    = (const float*)d_in[6];
  const float* boxf   = (const float*)d_in[7];
  const float* fmask  = (const float*)d_in[8];
  const float* bmask  = (const float*)d_in[9];
  const float* Wcf = (const float*)d_in[10];
  const float* Wco = (const float*)d_in[11];
  const float* Adf = (const float*)d_in[12];
  const float* Bdf = (const float*)d_in[13];
  const float* Wc1 = (const float*)d_in[14];
  const float* Ad1 = (const float*)d_in[15];
  const float* Bd1 = (const float*)d_in[16];
  const float* Wc2 = (const float*)d_in[17];
  const float* Ad2 = (const float*)d_in[18];
  const float* Bd2 = (const float*)d_in[19];
  const float* Wc3 = (const float*)d_in[20];
  const float* Ad3 = (const float*)d_in[21];
  const float* Bd3 = (const float*)d_in[22];
  const float* Wc4 = (const float*)d_in[23];
  const float* Ad4 = (const float*)d_in[24];
  const float* Bd4 = (const float*)d_in[25];

  float* ws = (float*)d_ws;
  float* P1    = ws + 0;          // 4096
  float* F0    = ws + 4096;       // 98304  (stride 48, padded)
  unsigned short* K2CF = (unsigned short*)(ws + 102400);  // 2304x32 bf16 T (73728 us = 36864 f)
  float* K2CO  = ws + 176128;     // 3072 f  (96 x 32 fp32)
  unsigned short* K2C1 = (unsigned short*)(ws + 179200);  // 4608x64 bf16 T (294912 us = 147456 f)
  unsigned short* K2C2 = (unsigned short*)(ws + 474112);  // 3072x64 bf16 T (98304 f)
  unsigned short* K2C3 = (unsigned short*)(ws + 670720);  // 98304 f
  float* K2C4  = ws + 867328;     // 6144 f  (3072 x 2 fp32)
  float* WFl   = ws + 873472;     // 1048576
  int*   PFl   = (int*)(ws + 1922048);   // 1048576
  int*   CNTF  = (int*)(ws + 2970624);   // 2048
  int*   CNTO  = (int*)(ws + 2972672);   // 2048
  float* IN1   = ws + 2974720;    // 196608 (2048 x 96)
  float* IN2   = ws + 3171328;    // 131072
  float* IN3   = ws + 3302400;    // 131072
  float* IN4   = ws + 3433472;    // 131072
  float* OUTA  = ws + 3564544;    // 131072
  float* OUTB  = ws + 3695616;    // 131072
  float* MO    = ws + 3826688;    // 196608 (box M fp32: 2048 x 96)
  float* GPART = ws + 4027392;    // 2097152 (max 16 x 2048 x 64)
  float* GPF   = GPART;           // 12 x 2048 x 32 (stage0 fluid partials)
  float* GPO   = GPART + 786432;  // 6 x 2048 x 32 (stage0 box partials)
  unsigned short* MBUF = (unsigned short*)(ws + 6124544); // bf16 2048 x 4608 max (4718592 f space avail)
  float* WOl   = ws + 15561728;   // 1048576
  int*   POl   = (int*)(ws + 16610304);  // 1048576

  setup_kernel<<<761, 256, 0, stream>>>(p0, v0, a, other, v0_enc, P1, F0,
                                        Wcf, K2CF, Wco, K2CO, Wc1, K2C1,
                                        Wc2, K2C2, Wc3, K2C3, Wc4, K2C4);
  pairs_all<<<1024, 256, 0, stream>>>(P1, P1, fmask, WFl, PFl, CNTF,
                                      box, bmask, WOl, POl, CNTO);

  // stage 0: box conv fp32; fluid conv bf16 MFMA
  accum_lds<2, 32, 64><<<64, 64, 0, stream>>>(WOl, POl, CNTO, boxf, MO);
  gemm_tiled<32><<<dim3(32, 6), 256, 0, stream>>>(MO, K2CO, GPO, 96, 16);
  accum4<48, 4, 192, true><<<512, 192, 0, stream>>>(WFl, PFl, CNTF, F0, MBUF);
  gemm_mfma<32><<<dim3(64, 3), 256, 0, stream>>>(MBUF, K2CF, GPF, 2304, 192);   // SPLIT=12
  epilogue0<<<384, 256, 0, stream>>>(GPF, GPO, F0, Adf, Bdf, IN1, 12, 6);

  // layer 1: I=48 -> O=32
  accum4<96, 2, 192, true><<<1024, 192, 0, stream>>>(WFl, PFl, CNTF, IN1, MBUF);
  gemm_mfma<64><<<dim3(64, 4), 256, 0, stream>>>(MBUF, K2C1, GPART, 4608, 288); // SPLIT=16
  epilogueL<<<256, 256, 0, stream>>>(GPART, 16, IN1, 48, Ad1, Bd1, nullptr, 0, OUTA, IN2);

  // layer 2: I=32 -> O=32, residual
  accum4<64, 3, 192, true><<<683, 192, 0, stream>>>(WFl, PFl, CNTF, IN2, MBUF);
  gemm_mfma<64><<<dim3(64, 4), 256, 0, stream>>>(MBUF, K2C2, GPART, 3072, 192); // SPLIT=16
  epilogueL<<<256, 256, 0, stream>>>(GPART, 16, IN2, 32, Ad2, Bd2, OUTA, 1, OUTB, IN3);

  // layer 3: I=32 -> O=32, residual
  accum4<64, 3, 192, true><<<683, 192, 0, stream>>>(WFl, PFl, CNTF, IN3, MBUF);
  gemm_mfma<64><<<dim3(64, 4), 256, 0, stream>>>(MBUF, K2C3, GPART, 3072, 192); // SPLIT=16
  epilogueL<<<256, 256, 0, stream>>>(GPART, 16, IN3, 32, Ad3, Bd3, OUTB, 1, OUTA, IN4);

  // layer 4: I=32 -> O=1, fused thin GEMM + apply_correction (bf16 M)
  accum4<64, 3, 192, true><<<683, 192, 0, stream>>>(WFl, PFl, CNTF, IN4, MBUF);
  gemm4_final<<<512, 256, 0, stream>>>(MBUF, K2C4, IN4, Ad4, Bd4, P1, p0, (float*)d_out);
}